// Round 5
// baseline (154.195 us; speedup 1.0000x reference)
//
#include <hip/hip_runtime.h>
#include <hip/hip_bf16.h>
#include <hip/hip_fp16.h>

typedef unsigned short ushort_t;
typedef unsigned int uint_t;
typedef __attribute__((ext_vector_type(8))) short short8;
typedef __attribute__((ext_vector_type(4))) float f32x4;
typedef __attribute__((ext_vector_type(4))) unsigned int uint4v;
typedef __attribute__((ext_vector_type(2))) _Float16 half2v;

#define FLAG_MAGIC 0x13579BDFu

#if defined(__has_builtin)
#if __has_builtin(__builtin_amdgcn_fdot2)
#define HAVE_FDOT2 1
#endif
#endif

__device__ __forceinline__ ushort_t f2bf(float f) {
    unsigned v;
    __builtin_memcpy(&v, &f, 4);
    unsigned r = (v + 0x7FFFu + ((v >> 16) & 1u)) >> 16;  // RNE
    return (ushort_t)r;
}

// Single fused kernel. Grid = 256 blocks x 512 threads (1 block/CU guaranteed).
// Block bid: b = bid>>5 (batch), j2 = bid&31.
// Producer : s_proj rows n = 2*j2, 2*j2+1  (d-split x2, LDS combine) -> s2 (f16,
//            layout [b][h2][n] half2-pairs); 128 frags of per-b Wpack copy.
//            Then device-scope release store of flags[bid] = MAGIC.
//            Flags live in ws: harness poison (0xAA..) != MAGIC on every call.
// Barrier  : lanes 0..31 acquire-spin on the 32 flags of this b-group.
// Consumer : t0 = j2*32 (two 16-row t-tiles). Phase B: bf16 MFMA f_proj tiles
//            -> f_lds (f16). Phase C: out = sum_h relu(f+s)*w + b_head via
//            pk_f16 add/max + v_dot2_f32_f16, fp32 accum.
__global__ __launch_bounds__(512, 2) void asd_fused(
        const float* __restrict__ feat,
        const float* __restrict__ slots,
        const float* __restrict__ Wproj,
        const float* __restrict__ bproj,
        const float* __restrict__ whead,
        const float* __restrict__ bhead,
        float* __restrict__ out,
        ushort_t* __restrict__ s2,
        ushort_t* __restrict__ wpackAll,
        uint_t* __restrict__ flags) {
    __shared__ float    sl[512];           // 2 slot rows x 256 d
    __shared__ float    part[256];         // d-half-1 partials
    __shared__ uint_t   s2_lds[64 * 68];   // [h2][n] half2-as-uint, stride 68
    __shared__ ushort_t f_lds[32 * 132];   // [t][h] f16, 32 rows, stride 132
    __shared__ uint_t   w2_lds[64];        // w_head as half2

    int tid = threadIdx.x;
    int bid = blockIdx.x;
    int b   = bid >> 5;
    int j2  = bid & 31;

    // ================= producer =================
    int n0 = j2 * 2;
    if (tid < 256) {
        float2 v = ((const float2*)(slots + (b * 64 + n0) * 256))[tid];
        sl[2 * tid]     = v.x;
        sl[2 * tid + 1] = v.y;
    }
    __syncthreads();
    {
        int dh = tid >> 8;               // d-half 0/1
        int nl = (tid >> 7) & 1;         // local n 0/1
        int h  = tid & 127;
        const float* Wcol = Wproj + 256 * 128 + dh * 128 * 128 + h;  // W_s
        const float* sr   = sl + nl * 256 + dh * 128;
        float acc = 0.f;
        #pragma unroll 16
        for (int d = 0; d < 128; ++d)
            acc += sr[d] * Wcol[d * 128];
        if (dh) part[nl * 128 + h] = acc;
        __syncthreads();
        if (!dh) {
            float v = acc + part[nl * 128 + h] + bproj[h];
            _Float16 hv = (_Float16)v;
            ushort_t u;
            __builtin_memcpy(&u, &hv, 2);
            int n = n0 + nl;
            s2[b * 8192 + (h >> 1) * 128 + n * 2 + (h & 1)] = u;
        }
    }
    // per-b Wpack copy: this block does frags f = j2*128 .. j2*128+127
    ushort_t* wpb = wpackAll + b * 32768;
    if (tid < 128) {
        int f   = j2 * 128 + tid;
        int l   = f & 63;
        int idx = f >> 6;
        int kb  = idx >> 3, nt = idx & 7;
        int r0  = kb * 32 + ((l >> 4) << 3);
        int c   = nt * 16 + (l & 15);
        short8 frag;
        #pragma unroll
        for (int i = 0; i < 8; ++i)
            frag[i] = (short)f2bf(Wproj[(r0 + i) * 128 + c]);
        ((short8*)wpb)[f] = frag;
    }
    __threadfence();
    __syncthreads();
    if (tid == 0)
        __hip_atomic_store(&flags[bid], FLAG_MAGIC, __ATOMIC_RELEASE,
                           __HIP_MEMORY_SCOPE_AGENT);

    // ================= group barrier =================
    if (tid < 32) {
        while (__hip_atomic_load(&flags[b * 32 + tid], __ATOMIC_ACQUIRE,
                                 __HIP_MEMORY_SCOPE_AGENT) != FLAG_MAGIC)
            __builtin_amdgcn_s_sleep(2);
    }
    __threadfence();
    __syncthreads();

    // ================= consumer =================
    // stage s2[b] (64 h2 x 64 n half2 = 16 KB) into LDS, padded rows
    const uint4v* src = (const uint4v*)(s2 + b * 8192);
    #pragma unroll
    for (int r = 0; r < 2; ++r) {
        int i4 = r * 512 + tid;            // 1024 16B chunks
        int h2 = i4 >> 4, c = i4 & 15;
        *(uint4v*)(s2_lds + h2 * 68 + c * 4) = src[i4];
    }
    if (tid < 64) {
        half2v w2 = { (_Float16)whead[2 * tid], (_Float16)whead[2 * tid + 1] };
        uint_t u;
        __builtin_memcpy(&u, &w2, 4);
        w2_lds[tid] = u;
    }
    float bh = bhead[0];

    // ---- phase B: two 16-row f_proj tiles via bf16 MFMA ----
    int t0 = j2 * 32;
    {
        int w    = tid >> 6;               // wave 0..7
        int l    = tid & 63;
        int tile = w >> 2;                 // 0/1: which 16-row t-tile
        int nt0  = 2 * (w & 3);            // 2 h-tiles of 16 per wave
        int m = l & 15, q = l >> 4;
        f32x4 acc0 = {0.f, 0.f, 0.f, 0.f};
        f32x4 acc1 = {0.f, 0.f, 0.f, 0.f};
        const short8* Wp = (const short8*)wpb;
        #pragma unroll
        for (int kb = 0; kb < 8; ++kb) {
            const float* arow =
                feat + (b * 1024 + t0 + tile * 16 + m) * 256 + kb * 32 + q * 8;
            f32x4 af0 = *(const f32x4*)arow;
            f32x4 af1 = *(const f32x4*)(arow + 4);
            __hip_bfloat162 c0 = __float22bfloat162_rn(make_float2(af0[0], af0[1]));
            __hip_bfloat162 c1 = __float22bfloat162_rn(make_float2(af0[2], af0[3]));
            __hip_bfloat162 c2 = __float22bfloat162_rn(make_float2(af1[0], af1[1]));
            __hip_bfloat162 c3 = __float22bfloat162_rn(make_float2(af1[2], af1[3]));
            uint_t u0, u1, u2, u3;
            __builtin_memcpy(&u0, &c0, 4);
            __builtin_memcpy(&u1, &c1, 4);
            __builtin_memcpy(&u2, &c2, 4);
            __builtin_memcpy(&u3, &c3, 4);
            uint4v au = {u0, u1, u2, u3};
            short8 A;
            __builtin_memcpy(&A, &au, 16);
            short8 B0 = Wp[(kb * 8 + nt0) * 64 + l];
            short8 B1 = Wp[(kb * 8 + nt0 + 1) * 64 + l];
            acc0 = __builtin_amdgcn_mfma_f32_16x16x32_bf16(A, B0, acc0, 0, 0, 0);
            acc1 = __builtin_amdgcn_mfma_f32_16x16x32_bf16(A, B1, acc1, 0, 0, 0);
        }
        #pragma unroll
        for (int r = 0; r < 4; ++r) {
            int row = tile * 16 + q * 4 + r;   // C/D: col=lane&15 -> h, row -> t
            _Float16 v0 = (_Float16)acc0[r];
            _Float16 v1 = (_Float16)acc1[r];
            ushort_t u0, u1;
            __builtin_memcpy(&u0, &v0, 2);
            __builtin_memcpy(&u1, &v1, 2);
            f_lds[row * 132 + nt0 * 16 + m]       = u0;
            f_lds[row * 132 + (nt0 + 1) * 16 + m] = u1;
        }
    }
    __syncthreads();

    // ---- phase C: relu-reduce over h (f16 packed + dot2, fp32 acc) ----
    int t  = tid >> 4;                     // 0..31
    int ng = tid & 15;                     // n = 4*ng..4*ng+3
    const ushort_t* fR = f_lds + t * 132;
    float a0 = bh, a1 = bh, a2 = bh, a3 = bh;
    const half2v hz = { (_Float16)0.f, (_Float16)0.f };
    #pragma unroll 8
    for (int h2 = 0; h2 < 64; ++h2) {
        uint_t fu = *(const uint_t*)(fR + 2 * h2);
        half2v f2;
        __builtin_memcpy(&f2, &fu, 4);
        uint4v s4 = *(const uint4v*)(s2_lds + h2 * 68 + 4 * ng);
        uint_t wu = w2_lds[h2];
        half2v w2;
        __builtin_memcpy(&w2, &wu, 4);
        float* accs[4] = {&a0, &a1, &a2, &a3};
        #pragma unroll
        for (int j = 0; j < 4; ++j) {
            uint_t su = s4[j];
            half2v sv;
            __builtin_memcpy(&sv, &su, 4);
            half2v x = f2 + sv;
            x = __builtin_elementwise_max(x, hz);
#ifdef HAVE_FDOT2
            *accs[j] = __builtin_amdgcn_fdot2(x, w2, *accs[j], false);
#else
            *accs[j] += (float)x[0] * (float)w2[0] + (float)x[1] * (float)w2[1];
#endif
        }
    }
    f32x4 o = {a0, a1, a2, a3};
    *(f32x4*)(out + (b * 1024 + t0 + t) * 64 + 4 * ng) = o;
}

extern "C" void kernel_launch(void* const* d_in, const int* in_sizes, int n_in,
                              void* d_out, int out_size, void* d_ws, size_t ws_size,
                              hipStream_t stream) {
    const float* feat  = (const float*)d_in[0];  // (8,1024,256) fp32
    const float* slots = (const float*)d_in[1];  // (8,64,256)   fp32
    const float* Wproj = (const float*)d_in[2];  // (512,128)    fp32
    const float* bproj = (const float*)d_in[3];  // (128,)       fp32
    const float* whead = (const float*)d_in[4];  // (128,)       fp32
    const float* bhead = (const float*)d_in[5];  // (1,)         fp32
    float* out = (float*)d_out;                  // (8,1024,64)  fp32

    ushort_t* s2       = (ushort_t*)d_ws;                       // 128 KB
    ushort_t* wpackAll = (ushort_t*)((char*)d_ws + 131072);     // 8 x 64 KB
    uint_t*   flags    = (uint_t*)((char*)d_ws + 655360);       // 256 x 4 B

    hipLaunchKernelGGL(asd_fused, dim3(256), dim3(512), 0, stream,
                       feat, slots, Wproj, bproj, whead, bhead,
                       out, s2, wpackAll, flags);
}

// Round 6
// 79.506 us; speedup vs baseline: 1.9394x; 1.9394x over previous
//
#include <hip/hip_runtime.h>
#include <hip/hip_bf16.h>
#include <hip/hip_fp16.h>

typedef unsigned short ushort_t;
typedef unsigned int uint_t;
typedef __attribute__((ext_vector_type(8))) short short8;
typedef __attribute__((ext_vector_type(4))) float f32x4;
typedef __attribute__((ext_vector_type(4))) unsigned int uint4v;
typedef __attribute__((ext_vector_type(2))) _Float16 half2v;

#if defined(__has_builtin)
#if __has_builtin(__builtin_amdgcn_fdot2)
#define HAVE_FDOT2 1
#endif
#endif

__device__ __forceinline__ ushort_t f2bf(float f) {
    unsigned v;
    __builtin_memcpy(&v, &f, 4);
    unsigned r = (v + 0x7FFFu + ((v >> 16) & 1u)) >> 16;  // RNE
    return (ushort_t)r;
}

// Kernel 1 (1024 threads/block):
//  blocks 0..255  : s_proj for (b, 2 slots). Threads = 4 d-quarters x 2n x 128h
//                   (4-way d-split -> 64-iter chains, 16 waves/CU; LDS tree-combine).
//                   Output f16 in k2's staging layout:
//                   s2[b*8192 + (h>>1)*128 + n*2 + (h&1)]   ([b][h2][n] half2)
//  blocks 256..259: pack W_f (rows 0..255 of W_proj) into bf16 MFMA B-frag order:
//                   Wpack[((kb*8+nt)*64+l)*8+i] = bf16(W_f[kb*32+(l>>4)*8+i][nt*16+(l&15)])
// NOTE (R5 lesson): no inter-block flags/spins — per-XCD L2 non-coherence makes
// acquire-spin on ws lines stall until eviction (~100 us idle). Two kernels it is.
__global__ __launch_bounds__(1024) void asd_k1(
        const float* __restrict__ slots,
        const float* __restrict__ Wproj,
        const float* __restrict__ bproj,
        ushort_t* __restrict__ s2,
        ushort_t* __restrict__ Wpack) {
    int bid = blockIdx.x;
    int tid = threadIdx.x;
    if (bid < 256) {
        __shared__ float sl[512];        // 2 slot rows x 256 d
        __shared__ float part[3][256];   // partials from d-quarters 1..3
        int b  = bid >> 5;
        int n0 = (bid & 31) * 2;
        const float* srow = slots + (b * 64 + n0) * 256;
        if (tid < 256) {
            float2 v = ((const float2*)srow)[tid];
            sl[2 * tid]     = v.x;
            sl[2 * tid + 1] = v.y;
        }
        __syncthreads();
        int dh = tid >> 8;               // d-quarter 0..3
        int nl = (tid >> 7) & 1;         // local n 0/1
        int h  = tid & 127;
        const float* Wcol = Wproj + 256 * 128 + dh * 64 * 128 + h;  // W_s = W_proj[256:]
        const float* sr   = sl + nl * 256 + dh * 64;
        float acc = 0.f;
        #pragma unroll 16
        for (int d = 0; d < 64; ++d)
            acc += sr[d] * Wcol[d * 128];
        if (dh) part[dh - 1][nl * 128 + h] = acc;
        __syncthreads();
        if (dh == 0) {
            float v = acc + part[0][nl * 128 + h] + part[1][nl * 128 + h]
                          + part[2][nl * 128 + h] + bproj[h];
            _Float16 hv = (_Float16)v;
            ushort_t u;
            __builtin_memcpy(&u, &hv, 2);
            int n = n0 + nl;
            s2[b * 8192 + (h >> 1) * 128 + n * 2 + (h & 1)] = u;
        }
    } else {
        int gid = (bid - 256) * 1024 + tid;  // 0..4095
        int l   = gid & 63;
        int idx = gid >> 6;                  // 0..63
        int kb  = idx >> 3, nt = idx & 7;
        int r0  = kb * 32 + ((l >> 4) << 3);
        int c   = nt * 16 + (l & 15);
        short8 frag;
        #pragma unroll
        for (int i = 0; i < 8; ++i)
            frag[i] = (short)f2bf(Wproj[(r0 + i) * 128 + c]);
        ((short8*)Wpack)[gid] = frag;
    }
}

// Kernel 2: one block per (b, 16-row t-tile). 256 threads = 4 waves.
// Phase B: MFMA 16x16x32 bf16 computes f_proj tile (16t x 128h) -> LDS f16
//          (stride 136 u16 = 272 B so phase-C b128 f-reads stay 16B-aligned).
// Phase C: h-blocked (8 h per step, b128 f-read) relu-reduce via
//          pk_f16 add/max + v_dot2_f32_f16, fp32 accum.
__global__ __launch_bounds__(256) void asd_k2(
        const float* __restrict__ feat,
        const ushort_t* __restrict__ s2g,
        const ushort_t* __restrict__ Wpack,
        const float* __restrict__ whead,
        const float* __restrict__ bhead,
        float* __restrict__ out) {
    __shared__ uint_t   s2_lds[64 * 68];   // [h2][n] half2-as-uint, row stride 68
    __shared__ ushort_t f_lds[16 * 136];   // [t][h] f16, row stride 136 (272 B)
    __shared__ uint_t   w2_lds[64];        // w_head as half2

    int tid = threadIdx.x;
    int bid = blockIdx.x;
    int b   = bid >> 6;
    int t0  = (bid & 63) << 4;

    if (tid < 64) {
        half2v w2 = { (_Float16)whead[2 * tid], (_Float16)whead[2 * tid + 1] };
        uint_t u;
        __builtin_memcpy(&u, &w2, 4);
        w2_lds[tid] = u;
    }
    // ---- stage s2[b] (64 h2 x 64 n half2 = 16 KB) into LDS, padded rows ----
    const uint4v* src = (const uint4v*)(s2g + b * 8192);
    #pragma unroll
    for (int r = 0; r < 4; ++r) {
        int i4 = r * 256 + tid;            // 1024 16B chunks
        int h2 = i4 >> 4, c = i4 & 15;
        *(uint4v*)(s2_lds + h2 * 68 + c * 4) = src[i4];
    }
    float bh = bhead[0];

    // ---- phase B: f_proj tile via bf16 MFMA ----
    int l = tid & 63;
    int w = tid >> 6;
    int m = l & 15, q = l >> 4;
    int nt0 = 2 * w;                       // each wave owns 2 h-tiles of 16
    f32x4 acc0 = {0.f, 0.f, 0.f, 0.f};
    f32x4 acc1 = {0.f, 0.f, 0.f, 0.f};
    const short8* Wp = (const short8*)Wpack;
    #pragma unroll
    for (int kb = 0; kb < 8; ++kb) {
        const float* arow = feat + (b * 1024 + t0 + m) * 256 + kb * 32 + q * 8;
        f32x4 af0 = *(const f32x4*)arow;
        f32x4 af1 = *(const f32x4*)(arow + 4);
        __hip_bfloat162 c0 = __float22bfloat162_rn(make_float2(af0[0], af0[1]));
        __hip_bfloat162 c1 = __float22bfloat162_rn(make_float2(af0[2], af0[3]));
        __hip_bfloat162 c2 = __float22bfloat162_rn(make_float2(af1[0], af1[1]));
        __hip_bfloat162 c3 = __float22bfloat162_rn(make_float2(af1[2], af1[3]));
        uint_t u0, u1, u2, u3;
        __builtin_memcpy(&u0, &c0, 4);
        __builtin_memcpy(&u1, &c1, 4);
        __builtin_memcpy(&u2, &c2, 4);
        __builtin_memcpy(&u3, &c3, 4);
        uint4v au = {u0, u1, u2, u3};
        short8 A;
        __builtin_memcpy(&A, &au, 16);
        short8 B0 = Wp[(kb * 8 + nt0) * 64 + l];
        short8 B1 = Wp[(kb * 8 + nt0 + 1) * 64 + l];
        acc0 = __builtin_amdgcn_mfma_f32_16x16x32_bf16(A, B0, acc0, 0, 0, 0);
        acc1 = __builtin_amdgcn_mfma_f32_16x16x32_bf16(A, B1, acc1, 0, 0, 0);
    }
    #pragma unroll
    for (int r = 0; r < 4; ++r) {
        int row = q * 4 + r;               // C/D: col=lane&15 -> h, row -> t
        _Float16 v0 = (_Float16)acc0[r];
        _Float16 v1 = (_Float16)acc1[r];
        ushort_t u0, u1;
        __builtin_memcpy(&u0, &v0, 2);
        __builtin_memcpy(&u1, &v1, 2);
        f_lds[row * 136 + nt0 * 16 + m]       = u0;
        f_lds[row * 136 + (nt0 + 1) * 16 + m] = u1;
    }
    __syncthreads();

    // ---- phase C: relu-reduce over h, blocked 8 h (4 h2) per step ----
    int t = tid >> 4, ng = tid & 15;       // thread owns (t, n = 4*ng..4*ng+3)
    const ushort_t* fR = f_lds + t * 136;  // 272 B rows -> 16B-aligned
    float a0 = bh, a1 = bh, a2 = bh, a3 = bh;
    const half2v hz = { (_Float16)0.f, (_Float16)0.f };
    #pragma unroll 4
    for (int hb = 0; hb < 16; ++hb) {
        uint4v fu4 = *(const uint4v*)(fR + 8 * hb);   // 8 f16 = 4 h2
        #pragma unroll
        for (int k = 0; k < 4; ++k) {
            int h2 = 4 * hb + k;
            half2v f2;
            uint_t fu = fu4[k];
            __builtin_memcpy(&f2, &fu, 4);
            uint4v s4 = *(const uint4v*)(s2_lds + h2 * 68 + 4 * ng);
            uint_t wu = w2_lds[h2];
            half2v w2;
            __builtin_memcpy(&w2, &wu, 4);
            float* accs[4] = {&a0, &a1, &a2, &a3};
            #pragma unroll
            for (int j = 0; j < 4; ++j) {
                uint_t su = s4[j];
                half2v sv;
                __builtin_memcpy(&sv, &su, 4);
                half2v x = f2 + sv;
                x = __builtin_elementwise_max(x, hz);
#ifdef HAVE_FDOT2
                *accs[j] = __builtin_amdgcn_fdot2(x, w2, *accs[j], false);
#else
                *accs[j] += (float)x[0] * (float)w2[0] + (float)x[1] * (float)w2[1];
#endif
            }
        }
    }
    f32x4 o = {a0, a1, a2, a3};
    *(f32x4*)(out + (b * 1024 + t0 + t) * 64 + 4 * ng) = o;
}

extern "C" void kernel_launch(void* const* d_in, const int* in_sizes, int n_in,
                              void* d_out, int out_size, void* d_ws, size_t ws_size,
                              hipStream_t stream) {
    const float* feat  = (const float*)d_in[0];  // (8,1024,256) fp32
    const float* slots = (const float*)d_in[1];  // (8,64,256)   fp32
    const float* Wproj = (const float*)d_in[2];  // (512,128)    fp32
    const float* bproj = (const float*)d_in[3];  // (128,)       fp32
    const float* whead = (const float*)d_in[4];  // (128,)       fp32
    const float* bhead = (const float*)d_in[5];  // (1,)         fp32
    float* out = (float*)d_out;                  // (8,1024,64)  fp32

    ushort_t* s2    = (ushort_t*)d_ws;                      // 8*64*128*2 = 128 KB
    ushort_t* Wpack = (ushort_t*)((char*)d_ws + 131072);    // 64 KB

    hipLaunchKernelGGL(asd_k1, dim3(260), dim3(1024), 0, stream,
                       slots, Wproj, bproj, s2, Wpack);
    hipLaunchKernelGGL(asd_k2, dim3(512), dim3(256), 0, stream,
                       feat, s2, Wpack, whead, bhead, out);
}